// Round 3
// baseline (1006.756 us; speedup 1.0000x reference)
//
#include <hip/hip_runtime.h>
#include <cstdint>
#include <cstddef>

typedef __bf16 bf16;
typedef __bf16 bf16x4 __attribute__((ext_vector_type(4)));
typedef __bf16 bf16x8 __attribute__((ext_vector_type(8)));
typedef float  fx4    __attribute__((ext_vector_type(4)));

// Problem dims (fixed): B=4, S=2048, D=1024, H=8, E=4, DH=128, K_route=2

__global__ __launch_bounds__(256) void f32_to_bf16(const float* __restrict__ src,
                                                   bf16* __restrict__ dst, int n) {
  int i = blockIdx.x * 256 + threadIdx.x;
  if (i < n) dst[i] = (bf16)src[i];
}

// wvt layout [h][dh][e][k]  <- v_w[h][e][k][dh]   (per-head B^T: N=dh=128, K'=e*1024+k)
__global__ __launch_bounds__(256) void make_wvt(const float* __restrict__ v_w,
                                                bf16* __restrict__ wvt) {
  int i = blockIdx.x * 256 + threadIdx.x;           // 4194304
  int k = i & 1023, e = (i >> 10) & 3, dh = (i >> 12) & 127, h = i >> 19;
  wvt[i] = (bf16)v_w[(((size_t)(h * 4 + e) * 1024) + k) * 128 + dh];
}

// wot layout [d][h][e][dh]  <- o_w[h][e][dh][d]   (B^T: N=d=1024, K'=(h*4+e)*128+dh)
__global__ __launch_bounds__(256) void make_wot(const float* __restrict__ o_w,
                                                bf16* __restrict__ wot) {
  int i = blockIdx.x * 256 + threadIdx.x;           // 4194304
  int dh = i & 127, e = (i >> 7) & 3, h = (i >> 9) & 7, d = i >> 12;
  wot[i] = (bf16)o_w[(((size_t)(h * 4 + e) * 128) + dh) * 1024 + d];
}

// ---------------- gating: sigmoid + top-2 of 4 per (token, head), f64 for exact ranking --------
__global__ __launch_bounds__(256) void gating(const float* __restrict__ q_src,
                                              const float* __restrict__ k_src,
                                              const float* __restrict__ sel_v_w,
                                              const float* __restrict__ sel_o_w,
                                              const float* __restrict__ bias_v,
                                              const float* __restrict__ bias_o,
                                              float* __restrict__ gate_v,
                                              float* __restrict__ gate_o,
                                              float* __restrict__ d_out) {
  int m = blockIdx.x, g = blockIdx.y;
  const float* x = g ? q_src : k_src;
  const float* w = g ? sel_o_w : sel_v_w;
  const float* bias = g ? bias_o : bias_v;
  float* gate = g ? gate_o : gate_v;
  float* idxo = d_out + 8388608 + g * 131072;       // v_idx then o_idx, as float values

  __shared__ float xs[1024];
  __shared__ double part_s[32][8];
  __shared__ double sel_s[32];
  int t = threadIdx.x;
  #pragma unroll
  for (int p = 0; p < 4; p++) xs[t + p * 256] = x[(size_t)m * 1024 + t + p * 256];
  __syncthreads();
  int he = t >> 3, pp = t & 7;
  const float* wrow = w + he * 1024;
  double acc = 0.0;
  for (int j = 0; j < 128; j++) { int k = pp + j * 8; acc += (double)xs[k] * (double)wrow[k]; }
  part_s[he][pp] = acc;
  __syncthreads();
  if (t < 32) {
    double tot = 0.0;
    #pragma unroll
    for (int j = 0; j < 8; j++) tot += part_s[t][j];
    sel_s[t] = 1.0 / (1.0 + exp(-tot));
  }
  __syncthreads();
  if (t < 8) {
    double v[4], vbv[4];
    #pragma unroll
    for (int e = 0; e < 4; e++) { v[e] = sel_s[t * 4 + e]; vbv[e] = v[e] + (double)bias[e]; }
    int i0 = 0;
    for (int e = 1; e < 4; e++) if (vbv[e] > vbv[i0]) i0 = e;
    int i1 = -1; double best = -1e300;
    for (int e = 0; e < 4; e++) { if (e == i0) continue; if (vbv[e] > best) { best = vbv[e]; i1 = e; } }
    float* gp = gate + ((size_t)m * 8 + t) * 4;
    #pragma unroll
    for (int e = 0; e < 4; e++) {
      float gv = 0.f;
      if (e == i0) gv = (float)v[i0];
      else if (e == i1) gv = (float)v[i1];
      gp[e] = gv;
    }
    idxo[m * 16 + t * 2 + 0] = (float)i0;
    idxo[m * 16 + t * 2 + 1] = (float)i1;
  }
}

// ---------------- GEMM: C[M x N] = A' @ BT^T, bf16 MFMA 16x16x32, tile 128x128x64 ----------------
// MODE 0: A=bf16 src, BT=wq/wk (1024x1024); epilogue *scale -> bf16 [b,h,s,dh]
// MODE 1: per-head h=blockIdx.z: A'[m,e*1024+k]=vsb[m,k]*gate_v[m,h,e]; BT_h (128x4096);
//         epilogue (LDS transpose) -> vbT bf16 [b,h,dh,s]
// MODE 2: A'[m,(h*4+e)*128+dh]=outb[m,h,dh]*gate_o[m,h,e]; BT (1024x4096); epilogue f32 -> d_out
template <int MODE>
__global__ __launch_bounds__(256, 3) void gemm_moe(const bf16* __restrict__ Abf,
                                                   const bf16* __restrict__ BT,
                                                   const float* __restrict__ gate,
                                                   bf16* __restrict__ Cbf,
                                                   float* __restrict__ Cf32,
                                                   float scale) {
  constexpr int KDIM = (MODE == 0) ? 1024 : 4096;
  __shared__ __align__(16) bf16 smem[18432];     // As: [0,9216)  Bs: [9216,18432), stride 72
  bf16* Asp = smem;
  bf16* Bsp = smem + 9216;
  const int t = threadIdx.x;
  const int wave = t >> 6, lane = t & 63;
  const int wr = wave >> 1, wc = wave & 1;
  const int quad = lane >> 4, l16 = lane & 15;
  const int m0 = blockIdx.y * 128;
  const int n0 = blockIdx.x * 128;
  const int h = (MODE == 1) ? blockIdx.z : 0;
  const bf16* BTh = (MODE == 1) ? BT + (size_t)h * 128 * 4096 : BT;

  fx4 acc[4][4] = {};

  const int arow = t >> 3, acol = (t & 7) * 8;    // 32 rows x 64 cols/pass, 4 passes

  for (int k0 = 0; k0 < KDIM; k0 += 64) {
    #pragma unroll
    for (int p = 0; p < 4; p++) {
      int m = m0 + arow + p * 32;
      bf16x8 u;
      if (MODE == 0) {
        u = *(const bf16x8*)(Abf + (size_t)m * 1024 + k0 + acol);
      } else if (MODE == 1) {
        int e = k0 >> 10;
        float gv = gate[((size_t)m * 8 + h) * 4 + e];
        u = *(const bf16x8*)(Abf + (size_t)m * 1024 + (k0 & 1023) + acol);
        #pragma unroll
        for (int j = 0; j < 8; j++) u[j] = (bf16)((float)u[j] * gv);
      } else {
        int kk = k0 + acol;
        int hh = kk >> 9, e = (kk >> 7) & 3, dh = kk & 127;
        float gv = gate[((size_t)m * 8 + hh) * 4 + e];
        u = *(const bf16x8*)(Abf + ((size_t)m * 8 + hh) * 128 + dh);
        #pragma unroll
        for (int j = 0; j < 8; j++) u[j] = (bf16)((float)u[j] * gv);
      }
      *(bf16x8*)(Asp + (arow + p * 32) * 72 + acol) = u;
    }
    #pragma unroll
    for (int p = 0; p < 4; p++) {
      int n = n0 + arow + p * 32;
      *(float4*)(Bsp + (arow + p * 32) * 72 + acol) = *(const float4*)(BTh + (size_t)n * KDIM + k0 + acol);
    }
    __syncthreads();
    #pragma unroll
    for (int kk = 0; kk < 64; kk += 32) {
      bf16x8 af[4], bfr[4];
      #pragma unroll
      for (int i = 0; i < 4; i++) af[i]  = *(const bf16x8*)(Asp + (wr * 64 + i * 16 + l16) * 72 + kk + quad * 8);
      #pragma unroll
      for (int i = 0; i < 4; i++) bfr[i] = *(const bf16x8*)(Bsp + (wc * 64 + i * 16 + l16) * 72 + kk + quad * 8);
      #pragma unroll
      for (int mi = 0; mi < 4; mi++)
        #pragma unroll
        for (int ni = 0; ni < 4; ni++)
          acc[mi][ni] = __builtin_amdgcn_mfma_f32_16x16x32_bf16(af[mi], bfr[ni], acc[mi][ni], 0, 0, 0);
    }
    __syncthreads();
  }

  if (MODE == 1) {
    // transpose through LDS -> vbT[b,h,dh,s] with coalesced global writes
    __syncthreads();
    #pragma unroll
    for (int mi = 0; mi < 4; mi++)
      #pragma unroll
      for (int ni = 0; ni < 4; ni++) {
        int nl = wc * 64 + ni * 16 + l16;
        int ml = wr * 64 + mi * 16 + quad * 4;
        bf16x4 pk;
        #pragma unroll
        for (int r = 0; r < 4; r++) pk[r] = (bf16)acc[mi][ni][r];
        *(bf16x4*)(smem + nl * 136 + ml) = pk;   // T[n][m], stride 136
      }
    __syncthreads();
    int b = m0 >> 11, s0 = m0 & 2047;
    const int row = t >> 1, base = (t & 1) * 64;
    bf16* dst = Cbf + (((size_t)(b * 8 + h) * 128) + row) * 2048 + s0 + base;
    #pragma unroll
    for (int j = 0; j < 8; j++)
      *(float4*)(dst + j * 8) = *(float4*)(smem + row * 136 + base + j * 8);
    return;
  }

  // epilogue: C/D layout col=lane&15, row=quad*4+reg
  #pragma unroll
  for (int mi = 0; mi < 4; mi++)
    #pragma unroll
    for (int ni = 0; ni < 4; ni++)
      #pragma unroll
      for (int r = 0; r < 4; r++) {
        int m = m0 + wr * 64 + mi * 16 + quad * 4 + r;
        int n = n0 + wc * 64 + ni * 16 + l16;
        float v = acc[mi][ni][r] * scale;
        if (MODE == 0) {
          int b = m >> 11, s = m & 2047, hh = n >> 7, dh = n & 127;
          Cbf[(((size_t)(b * 8 + hh) * 2048 + s) << 7) + dh] = (bf16)v;
        } else {
          Cf32[(size_t)m * 1024 + n] = v;
        }
      }
}

// ---------------- flash attention (causal), per (b,h) x 64-row q-tile ----------------
__global__ __launch_bounds__(256, 3) void attn_kernel(const bf16* __restrict__ qb,
                                                      const bf16* __restrict__ kb,
                                                      const bf16* __restrict__ vbT,
                                                      bf16* __restrict__ outb) {
  const int qt = 31 - blockIdx.x;   // heavy blocks dispatch first
  const int bh = blockIdx.y;
  const int b = bh >> 3, h = bh & 7;
  __shared__ __align__(16) bf16 Ks[64][136];
  __shared__ __align__(16) bf16 VTs[128][72];
  __shared__ __align__(16) bf16 Ps[4][16][72];
  const int t = threadIdx.x, wave = t >> 6, lane = t & 63;
  const int quad = lane >> 4, l16 = lane & 15;
  const bf16* qbase  = qb  + (size_t)bh * 2048 * 128;
  const bf16* kbase  = kb  + (size_t)bh * 2048 * 128;
  const bf16* vtbase = vbT + (size_t)bh * 128 * 2048;

  // stage Q through Ks (one-time), read q-fragments into registers
  #pragma unroll
  for (int p = 0; p < 4; p++) {
    int c = t + p * 256;
    *(float4*)&Ks[c >> 4][(c & 15) * 8] =
        *(const float4*)(qbase + (size_t)(qt * 64 + (c >> 4)) * 128 + (c & 15) * 8);
  }
  __syncthreads();
  bf16x8 qf[4];
  #pragma unroll
  for (int dk = 0; dk < 4; dk++) qf[dk] = *(const bf16x8*)&Ks[wave * 16 + l16][dk * 32 + quad * 8];

  float m_run[4], l_run[4];
  fx4 acc_o[8] = {};
  #pragma unroll
  for (int r = 0; r < 4; r++) { m_run[r] = -1e30f; l_run[r] = 0.f; }

  float4 kreg[4], vreg[4];
  #pragma unroll
  for (int p = 0; p < 4; p++) {
    int c = t + p * 256;
    kreg[p] = *(const float4*)(kbase + (size_t)(c >> 4) * 128 + (c & 15) * 8);
    vreg[p] = *(const float4*)(vtbase + (size_t)(c >> 3) * 2048 + (c & 7) * 8);
  }

  for (int kt = 0; kt <= qt; kt++) {
    __syncthreads();                 // all waves done reading Ks/VTs (or qf on iter 0)
    #pragma unroll
    for (int p = 0; p < 4; p++) {
      int c = t + p * 256;
      *(float4*)&Ks[c >> 4][(c & 15) * 8] = kreg[p];
      *(float4*)&VTs[c >> 3][(c & 7) * 8] = vreg[p];
    }
    __syncthreads();
    if (kt < qt) {                   // prefetch next tile into registers during compute
      #pragma unroll
      for (int p = 0; p < 4; p++) {
        int c = t + p * 256;
        kreg[p] = *(const float4*)(kbase + (size_t)((kt + 1) * 64 + (c >> 4)) * 128 + (c & 15) * 8);
        vreg[p] = *(const float4*)(vtbase + (size_t)(c >> 3) * 2048 + (kt + 1) * 64 + (c & 7) * 8);
      }
    }

    fx4 accs[4] = {};
    #pragma unroll
    for (int ni = 0; ni < 4; ni++)
      #pragma unroll
      for (int dk = 0; dk < 4; dk++) {
        bf16x8 kf = *(const bf16x8*)&Ks[ni * 16 + l16][dk * 32 + quad * 8];
        accs[ni] = __builtin_amdgcn_mfma_f32_16x16x32_bf16(qf[dk], kf, accs[ni], 0, 0, 0);
      }

    if (kt == qt) {   // causal mask on the diagonal tile
      #pragma unroll
      for (int ni = 0; ni < 4; ni++)
        #pragma unroll
        for (int r = 0; r < 4; r++) {
          int qr = wave * 16 + quad * 4 + r;
          int kc = ni * 16 + l16;
          if (kc > qr) accs[ni][r] = -1e30f;
        }
    }

    // softmax in exp2 domain (log2e folded into Q scale); exp results overwrite accs
    #pragma unroll
    for (int r = 0; r < 4; r++) {
      float mx = fmaxf(fmaxf(accs[0][r], accs[1][r]), fmaxf(accs[2][r], accs[3][r]));
      #pragma unroll
      for (int s = 1; s < 16; s <<= 1) mx = fmaxf(mx, __shfl_xor(mx, s, 64));
      float m_new = fmaxf(m_run[r], mx);
      float alpha = __builtin_amdgcn_exp2f(m_run[r] - m_new);
      float rs = 0.f;
      #pragma unroll
      for (int ni = 0; ni < 4; ni++) {
        float p = __builtin_amdgcn_exp2f(accs[ni][r] - m_new);
        accs[ni][r] = p; rs += p;
      }
      #pragma unroll
      for (int s = 1; s < 16; s <<= 1) rs += __shfl_xor(rs, s, 64);
      l_run[r] = l_run[r] * alpha + rs;
      m_run[r] = m_new;
      #pragma unroll
      for (int nj = 0; nj < 8; nj++) acc_o[nj][r] *= alpha;
    }

    // P: C-layout -> LDS -> A-layout (per-wave region)
    #pragma unroll
    for (int ni = 0; ni < 4; ni++)
      #pragma unroll
      for (int r = 0; r < 4; r++)
        Ps[wave][quad * 4 + r][ni * 16 + l16] = (bf16)accs[ni][r];

    #pragma unroll
    for (int step = 0; step < 2; step++) {
      bf16x8 pf = *(const bf16x8*)&Ps[wave][l16][step * 32 + quad * 8];
      #pragma unroll
      for (int nj = 0; nj < 8; nj++) {
        bf16x8 vf = *(const bf16x8*)&VTs[nj * 16 + l16][step * 32 + quad * 8];
        acc_o[nj] = __builtin_amdgcn_mfma_f32_16x16x32_bf16(pf, vf, acc_o[nj], 0, 0, 0);
      }
    }
  }

  #pragma unroll
  for (int nj = 0; nj < 8; nj++)
    #pragma unroll
    for (int r = 0; r < 4; r++) {
      int s = qt * 64 + wave * 16 + quad * 4 + r;
      int token = b * 2048 + s;
      float o = acc_o[nj][r] / l_run[r];
      outb[((size_t)token * 8 + h) * 128 + nj * 16 + l16] = (bf16)o;
    }
}

// ---------------- launch ----------------
extern "C" void kernel_launch(void* const* d_in, const int* in_sizes, int n_in,
                              void* d_out, int out_size, void* d_ws, size_t ws_size,
                              hipStream_t stream) {
  const float* q_src  = (const float*)d_in[0];
  const float* k_src  = (const float*)d_in[1];
  const float* v_src  = (const float*)d_in[2];
  const float* wq     = (const float*)d_in[3];
  const float* wk     = (const float*)d_in[4];
  const float* sel_v_w = (const float*)d_in[5];
  const float* sel_o_w = (const float*)d_in[6];
  const float* v_w    = (const float*)d_in[7];
  const float* o_w    = (const float*)d_in[8];
  const float* bias_v = (const float*)d_in[9];
  const float* bias_o = (const float*)d_in[10];
  float* out = (float*)d_out;

  char* ws = (char*)d_ws;
  size_t off = 0;
  auto alloc = [&](size_t bytes) { char* p = ws + off; off += (bytes + 255) & ~(size_t)255; return p; };
  bf16* wqb   = (bf16*)alloc((size_t)1024 * 1024 * 2);
  bf16* wkb   = (bf16*)alloc((size_t)1024 * 1024 * 2);
  bf16* wvt   = (bf16*)alloc((size_t)8 * 128 * 4 * 1024 * 2);
  bf16* wot   = (bf16*)alloc((size_t)1024 * 4096 * 2);
  float* gate_v = (float*)alloc((size_t)8192 * 32 * 4);
  float* gate_o = (float*)alloc((size_t)8192 * 32 * 4);
  bf16* qsb   = (bf16*)alloc((size_t)8192 * 1024 * 2);   // bf16 copies of srcs
  bf16* ksb   = (bf16*)alloc((size_t)8192 * 1024 * 2);
  bf16* vsb   = (bf16*)alloc((size_t)8192 * 1024 * 2);
  bf16* qb    = (bf16*)alloc((size_t)8192 * 1024 * 2);   // [b,h,s,dh]
  bf16* kb    = (bf16*)alloc((size_t)8192 * 1024 * 2);   // [b,h,s,dh]
  bf16* vbT   = (bf16*)alloc((size_t)8192 * 1024 * 2);   // [b,h,dh,s]
  bf16* outb  = (bf16*)alloc((size_t)8192 * 1024 * 2);   // [b,s,h,dh]

  f32_to_bf16<<<4096, 256, 0, stream>>>(wq, wqb, 1024 * 1024);
  f32_to_bf16<<<4096, 256, 0, stream>>>(wk, wkb, 1024 * 1024);
  f32_to_bf16<<<32768, 256, 0, stream>>>(q_src, qsb, 8388608);
  f32_to_bf16<<<32768, 256, 0, stream>>>(k_src, ksb, 8388608);
  f32_to_bf16<<<32768, 256, 0, stream>>>(v_src, vsb, 8388608);
  make_wvt<<<16384, 256, 0, stream>>>(v_w, wvt);
  make_wot<<<16384, 256, 0, stream>>>(o_w, wot);
  gating<<<dim3(8192, 2), 256, 0, stream>>>(q_src, k_src, sel_v_w, sel_o_w,
                                            bias_v, bias_o, gate_v, gate_o, out);

  const float ssq = 0.29730177875068026f;            // 128^-0.25 (applied to both q and k)
  const float log2e = 1.4426950408889634f;
  gemm_moe<0><<<dim3(8, 64), 256, 0, stream>>>(qsb, wqb, nullptr, qb, nullptr, ssq * log2e);
  gemm_moe<0><<<dim3(8, 64), 256, 0, stream>>>(ksb, wkb, nullptr, kb, nullptr, ssq);
  gemm_moe<1><<<dim3(1, 64, 8), 256, 0, stream>>>(vsb, wvt, gate_v, vbT, nullptr, 1.0f);
  attn_kernel<<<dim3(32, 32), 256, 0, stream>>>(qb, kb, vbT, outb);
  gemm_moe<2><<<dim3(8, 64), 256, 0, stream>>>(outb, wot, gate_o, nullptr, out, 1.0f);
}

// Round 4
// 1003.263 us; speedup vs baseline: 1.0035x; 1.0035x over previous
//
#include <hip/hip_runtime.h>
#include <cstdint>
#include <cstddef>

typedef __bf16 bf16;
typedef __bf16 bf16x4 __attribute__((ext_vector_type(4)));
typedef __bf16 bf16x8 __attribute__((ext_vector_type(8)));
typedef float  fx4    __attribute__((ext_vector_type(4)));

// Problem dims (fixed): B=4, S=2048, D=1024, H=8, E=4, DH=128, K_route=2

__global__ __launch_bounds__(256) void f32_to_bf16(const float* __restrict__ src,
                                                   bf16* __restrict__ dst, int n) {
  int i = blockIdx.x * 256 + threadIdx.x;
  if (i < n) dst[i] = (bf16)src[i];
}

// wvt layout [h][dh][e][k]  <- v_w[h][e][k][dh]   (per-head B^T: N=dh=128, K'=e*1024+k)
__global__ __launch_bounds__(256) void make_wvt(const float* __restrict__ v_w,
                                                bf16* __restrict__ wvt) {
  int i = blockIdx.x * 256 + threadIdx.x;           // 4194304
  int k = i & 1023, e = (i >> 10) & 3, dh = (i >> 12) & 127, h = i >> 19;
  wvt[i] = (bf16)v_w[(((size_t)(h * 4 + e) * 1024) + k) * 128 + dh];
}

// wot layout [d][h][e][dh]  <- o_w[h][e][dh][d]   (B^T: N=d=1024, K'=(h*4+e)*128+dh)
__global__ __launch_bounds__(256) void make_wot(const float* __restrict__ o_w,
                                                bf16* __restrict__ wot) {
  int i = blockIdx.x * 256 + threadIdx.x;           // 4194304
  int dh = i & 127, e = (i >> 7) & 3, h = (i >> 9) & 7, d = i >> 12;
  wot[i] = (bf16)o_w[(((size_t)(h * 4 + e) * 128) + dh) * 1024 + d];
}

// ---------------- gating: sigmoid + top-2 of 4 per (token, head), f64 for exact ranking --------
__global__ __launch_bounds__(256) void gating(const float* __restrict__ q_src,
                                              const float* __restrict__ k_src,
                                              const float* __restrict__ sel_v_w,
                                              const float* __restrict__ sel_o_w,
                                              const float* __restrict__ bias_v,
                                              const float* __restrict__ bias_o,
                                              float* __restrict__ gate_v,
                                              float* __restrict__ gate_o,
                                              float* __restrict__ d_out) {
  int m = blockIdx.x, g = blockIdx.y;
  const float* x = g ? q_src : k_src;
  const float* w = g ? sel_o_w : sel_v_w;
  const float* bias = g ? bias_o : bias_v;
  float* gate = g ? gate_o : gate_v;
  float* idxo = d_out + 8388608 + g * 131072;       // v_idx then o_idx, as float values

  __shared__ float xs[1024];
  __shared__ double part_s[32][8];
  __shared__ double sel_s[32];
  int t = threadIdx.x;
  #pragma unroll
  for (int p = 0; p < 4; p++) xs[t + p * 256] = x[(size_t)m * 1024 + t + p * 256];
  __syncthreads();
  int he = t >> 3, pp = t & 7;
  const float* wrow = w + he * 1024;
  double acc = 0.0;
  for (int j = 0; j < 128; j++) { int k = pp + j * 8; acc += (double)xs[k] * (double)wrow[k]; }
  part_s[he][pp] = acc;
  __syncthreads();
  if (t < 32) {
    double tot = 0.0;
    #pragma unroll
    for (int j = 0; j < 8; j++) tot += part_s[t][j];
    sel_s[t] = 1.0 / (1.0 + exp(-tot));
  }
  __syncthreads();
  if (t < 8) {
    double v[4], vbv[4];
    #pragma unroll
    for (int e = 0; e < 4; e++) { v[e] = sel_s[t * 4 + e]; vbv[e] = v[e] + (double)bias[e]; }
    int i0 = 0;
    for (int e = 1; e < 4; e++) if (vbv[e] > vbv[i0]) i0 = e;
    int i1 = -1; double best = -1e300;
    for (int e = 0; e < 4; e++) { if (e == i0) continue; if (vbv[e] > best) { best = vbv[e]; i1 = e; } }
    float* gp = gate + ((size_t)m * 8 + t) * 4;
    #pragma unroll
    for (int e = 0; e < 4; e++) {
      float gv = 0.f;
      if (e == i0) gv = (float)v[i0];
      else if (e == i1) gv = (float)v[i1];
      gp[e] = gv;
    }
    idxo[m * 16 + t * 2 + 0] = (float)i0;
    idxo[m * 16 + t * 2 + 1] = (float)i1;
  }
}

// ---------------- GEMM: C[M x N] = A' @ BT^T, bf16 MFMA 16x16x32, tile 128x128x64 ----------------
// MODE 0: A=bf16 src, BT=wq/wk (1024x1024); epilogue *scale -> bf16 [b,h,s,dh]
// MODE 1: per-head h=blockIdx.z: A'[m,e*1024+k]=vsb[m,k]*gate_v[m,h,e]; BT_h (128x4096);
//         epilogue (LDS transpose) -> vbT bf16 [b,h,dh,s]
// MODE 2: A'[m,(h*4+e)*128+dh]=outb[m,h,dh]*gate_o[m,h,e]; BT (1024x4096); epilogue f32 -> d_out
template <int MODE>
__global__ __launch_bounds__(256, 2) void gemm_moe(const bf16* __restrict__ Abf,
                                                   const bf16* __restrict__ BT,
                                                   const float* __restrict__ gate,
                                                   bf16* __restrict__ Cbf,
                                                   float* __restrict__ Cf32,
                                                   float scale) {
  constexpr int KDIM = (MODE == 0) ? 1024 : 4096;
  __shared__ __align__(16) bf16 smem[18432];     // As: [0,9216)  Bs: [9216,18432), stride 72
  bf16* Asp = smem;
  bf16* Bsp = smem + 9216;
  const int t = threadIdx.x;
  const int wave = t >> 6, lane = t & 63;
  const int wr = wave >> 1, wc = wave & 1;
  const int quad = lane >> 4, l16 = lane & 15;
  const int m0 = blockIdx.y * 128;
  const int n0 = blockIdx.x * 128;
  const int h = (MODE == 1) ? blockIdx.z : 0;
  const bf16* BTh = (MODE == 1) ? BT + (size_t)h * 128 * 4096 : BT;

  fx4 acc[4][4] = {};

  const int arow = t >> 3, acol = (t & 7) * 8;    // 32 rows x 64 cols/pass, 4 passes

  for (int k0 = 0; k0 < KDIM; k0 += 64) {
    #pragma unroll
    for (int p = 0; p < 4; p++) {
      int m = m0 + arow + p * 32;
      bf16x8 u;
      if (MODE == 0) {
        u = *(const bf16x8*)(Abf + (size_t)m * 1024 + k0 + acol);
      } else if (MODE == 1) {
        int e = k0 >> 10;
        float gv = gate[((size_t)m * 8 + h) * 4 + e];
        u = *(const bf16x8*)(Abf + (size_t)m * 1024 + (k0 & 1023) + acol);
        #pragma unroll
        for (int j = 0; j < 8; j++) u[j] = (bf16)((float)u[j] * gv);
      } else {
        int kk = k0 + acol;
        int hh = kk >> 9, e = (kk >> 7) & 3, dh = kk & 127;
        float gv = gate[((size_t)m * 8 + hh) * 4 + e];
        u = *(const bf16x8*)(Abf + ((size_t)m * 8 + hh) * 128 + dh);
        #pragma unroll
        for (int j = 0; j < 8; j++) u[j] = (bf16)((float)u[j] * gv);
      }
      *(bf16x8*)(Asp + (arow + p * 32) * 72 + acol) = u;
    }
    #pragma unroll
    for (int p = 0; p < 4; p++) {
      int n = n0 + arow + p * 32;
      *(float4*)(Bsp + (arow + p * 32) * 72 + acol) = *(const float4*)(BTh + (size_t)n * KDIM + k0 + acol);
    }
    __syncthreads();
    #pragma unroll
    for (int kk = 0; kk < 64; kk += 32) {
      bf16x8 af[4], bfr[4];
      #pragma unroll
      for (int i = 0; i < 4; i++) af[i]  = *(const bf16x8*)(Asp + (wr * 64 + i * 16 + l16) * 72 + kk + quad * 8);
      #pragma unroll
      for (int i = 0; i < 4; i++) bfr[i] = *(const bf16x8*)(Bsp + (wc * 64 + i * 16 + l16) * 72 + kk + quad * 8);
      #pragma unroll
      for (int mi = 0; mi < 4; mi++)
        #pragma unroll
        for (int ni = 0; ni < 4; ni++)
          acc[mi][ni] = __builtin_amdgcn_mfma_f32_16x16x32_bf16(af[mi], bfr[ni], acc[mi][ni], 0, 0, 0);
    }
    __syncthreads();
  }

  if (MODE == 1) {
    // transpose through LDS -> vbT[b,h,dh,s] with coalesced global writes
    #pragma unroll
    for (int mi = 0; mi < 4; mi++)
      #pragma unroll
      for (int ni = 0; ni < 4; ni++) {
        int nl = wc * 64 + ni * 16 + l16;
        int ml = wr * 64 + mi * 16 + quad * 4;
        bf16x4 pk;
        #pragma unroll
        for (int r = 0; r < 4; r++) pk[r] = (bf16)acc[mi][ni][r];
        *(bf16x4*)(smem + nl * 136 + ml) = pk;   // T[n][m], stride 136
      }
    __syncthreads();
    int b = m0 >> 11, s0 = m0 & 2047;
    const int row = t >> 1, base = (t & 1) * 64;
    bf16* dst = Cbf + (((size_t)(b * 8 + h) * 128) + row) * 2048 + s0 + base;
    #pragma unroll
    for (int j = 0; j < 8; j++)
      *(float4*)(dst + j * 8) = *(float4*)(smem + row * 136 + base + j * 8);
    return;
  }

  // epilogue: C/D layout col=lane&15, row=quad*4+reg
  #pragma unroll
  for (int mi = 0; mi < 4; mi++)
    #pragma unroll
    for (int ni = 0; ni < 4; ni++)
      #pragma unroll
      for (int r = 0; r < 4; r++) {
        int m = m0 + wr * 64 + mi * 16 + quad * 4 + r;
        int n = n0 + wc * 64 + ni * 16 + l16;
        float v = acc[mi][ni][r] * scale;
        if (MODE == 0) {
          int b = m >> 11, s = m & 2047, hh = n >> 7, dh = n & 127;
          Cbf[(((size_t)(b * 8 + hh) * 2048 + s) << 7) + dh] = (bf16)v;
        } else {
          Cf32[(size_t)m * 1024 + n] = v;
        }
      }
}

// ---------------- flash attention (causal), per (b,h) x 64-row q-tile ----------------
// launch_bounds(256,2): 2 blocks/CU, 256-reg budget -> no scratch spill (round-3 lesson:
// (256,3) squeezed arch VGPRs to 80 and spilled 340 MB/call to scratch).
__global__ __launch_bounds__(256, 2) void attn_kernel(const bf16* __restrict__ qb,
                                                      const bf16* __restrict__ kb,
                                                      const bf16* __restrict__ vbT,
                                                      bf16* __restrict__ outb) {
  const int qt = 31 - blockIdx.x;   // heavy blocks dispatch first
  const int bh = blockIdx.y;
  const int b = bh >> 3, h = bh & 7;
  __shared__ __align__(16) bf16 Ks[64][136];
  __shared__ __align__(16) bf16 VTs[128][72];
  __shared__ __align__(16) bf16 Ps[4][16][72];
  const int t = threadIdx.x, wave = t >> 6, lane = t & 63;
  const int quad = lane >> 4, l16 = lane & 15;
  const bf16* qbase  = qb  + (size_t)bh * 2048 * 128;
  const bf16* kbase  = kb  + (size_t)bh * 2048 * 128;
  const bf16* vtbase = vbT + (size_t)bh * 128 * 2048;

  // stage Q through Ks (one-time), read q-fragments into registers
  #pragma unroll
  for (int p = 0; p < 4; p++) {
    int c = t + p * 256;
    *(float4*)&Ks[c >> 4][(c & 15) * 8] =
        *(const float4*)(qbase + (size_t)(qt * 64 + (c >> 4)) * 128 + (c & 15) * 8);
  }
  __syncthreads();
  bf16x8 qf[4];
  #pragma unroll
  for (int dk = 0; dk < 4; dk++) qf[dk] = *(const bf16x8*)&Ks[wave * 16 + l16][dk * 32 + quad * 8];

  float m_run[4], l_run[4];
  fx4 acc_o[8] = {};
  #pragma unroll
  for (int r = 0; r < 4; r++) { m_run[r] = -1e30f; l_run[r] = 0.f; }

  float4 kreg[4], vreg[4];
  #pragma unroll
  for (int p = 0; p < 4; p++) {
    int c = t + p * 256;
    kreg[p] = *(const float4*)(kbase + (size_t)(c >> 4) * 128 + (c & 15) * 8);
    vreg[p] = *(const float4*)(vtbase + (size_t)(c >> 3) * 2048 + (c & 7) * 8);
  }

  for (int kt = 0; kt <= qt; kt++) {
    __syncthreads();                 // all waves done reading Ks/VTs (or qf on iter 0)
    #pragma unroll
    for (int p = 0; p < 4; p++) {
      int c = t + p * 256;
      *(float4*)&Ks[c >> 4][(c & 15) * 8] = kreg[p];
      *(float4*)&VTs[c >> 3][(c & 7) * 8] = vreg[p];
    }
    __syncthreads();
    if (kt < qt) {                   // prefetch next tile into registers during compute
      #pragma unroll
      for (int p = 0; p < 4; p++) {
        int c = t + p * 256;
        kreg[p] = *(const float4*)(kbase + (size_t)((kt + 1) * 64 + (c >> 4)) * 128 + (c & 15) * 8);
        vreg[p] = *(const float4*)(vtbase + (size_t)(c >> 3) * 2048 + (kt + 1) * 64 + (c & 7) * 8);
      }
    }

    fx4 accs[4] = {};
    #pragma unroll
    for (int ni = 0; ni < 4; ni++)
      #pragma unroll
      for (int dk = 0; dk < 4; dk++) {
        bf16x8 kf = *(const bf16x8*)&Ks[ni * 16 + l16][dk * 32 + quad * 8];
        accs[ni] = __builtin_amdgcn_mfma_f32_16x16x32_bf16(qf[dk], kf, accs[ni], 0, 0, 0);
      }

    if (kt == qt) {   // causal mask on the diagonal tile
      #pragma unroll
      for (int ni = 0; ni < 4; ni++)
        #pragma unroll
        for (int r = 0; r < 4; r++) {
          int qr = wave * 16 + quad * 4 + r;
          int kc = ni * 16 + l16;
          if (kc > qr) accs[ni][r] = -1e30f;
        }
    }

    // softmax in exp2 domain (log2e folded into Q scale); exp results overwrite accs
    #pragma unroll
    for (int r = 0; r < 4; r++) {
      float mx = fmaxf(fmaxf(accs[0][r], accs[1][r]), fmaxf(accs[2][r], accs[3][r]));
      #pragma unroll
      for (int s = 1; s < 16; s <<= 1) mx = fmaxf(mx, __shfl_xor(mx, s, 64));
      float m_new = fmaxf(m_run[r], mx);
      float alpha = __builtin_amdgcn_exp2f(m_run[r] - m_new);
      float rs = 0.f;
      #pragma unroll
      for (int ni = 0; ni < 4; ni++) {
        float p = __builtin_amdgcn_exp2f(accs[ni][r] - m_new);
        accs[ni][r] = p; rs += p;
      }
      #pragma unroll
      for (int s = 1; s < 16; s <<= 1) rs += __shfl_xor(rs, s, 64);
      l_run[r] = l_run[r] * alpha + rs;
      m_run[r] = m_new;
      #pragma unroll
      for (int nj = 0; nj < 8; nj++) acc_o[nj][r] *= alpha;
    }

    // P: C-layout -> LDS -> A-layout (per-wave region)
    #pragma unroll
    for (int ni = 0; ni < 4; ni++)
      #pragma unroll
      for (int r = 0; r < 4; r++)
        Ps[wave][quad * 4 + r][ni * 16 + l16] = (bf16)accs[ni][r];

    #pragma unroll
    for (int step = 0; step < 2; step++) {
      bf16x8 pf = *(const bf16x8*)&Ps[wave][l16][step * 32 + quad * 8];
      #pragma unroll
      for (int nj = 0; nj < 8; nj++) {
        bf16x8 vf = *(const bf16x8*)&VTs[nj * 16 + l16][step * 32 + quad * 8];
        acc_o[nj] = __builtin_amdgcn_mfma_f32_16x16x32_bf16(pf, vf, acc_o[nj], 0, 0, 0);
      }
    }
  }

  #pragma unroll
  for (int nj = 0; nj < 8; nj++)
    #pragma unroll
    for (int r = 0; r < 4; r++) {
      int s = qt * 64 + wave * 16 + quad * 4 + r;
      int token = b * 2048 + s;
      float o = acc_o[nj][r] / l_run[r];
      outb[((size_t)token * 8 + h) * 128 + nj * 16 + l16] = (bf16)o;
    }
}

// ---------------- launch ----------------
extern "C" void kernel_launch(void* const* d_in, const int* in_sizes, int n_in,
                              void* d_out, int out_size, void* d_ws, size_t ws_size,
                              hipStream_t stream) {
  const float* q_src  = (const float*)d_in[0];
  const float* k_src  = (const float*)d_in[1];
  const float* v_src  = (const float*)d_in[2];
  const float* wq     = (const float*)d_in[3];
  const float* wk     = (const float*)d_in[4];
  const float* sel_v_w = (const float*)d_in[5];
  const float* sel_o_w = (const float*)d_in[6];
  const float* v_w    = (const float*)d_in[7];
  const float* o_w    = (const float*)d_in[8];
  const float* bias_v = (const float*)d_in[9];
  const float* bias_o = (const float*)d_in[10];
  float* out = (float*)d_out;

  char* ws = (char*)d_ws;
  size_t off = 0;
  auto alloc = [&](size_t bytes) { char* p = ws + off; off += (bytes + 255) & ~(size_t)255; return p; };
  bf16* wqb   = (bf16*)alloc((size_t)1024 * 1024 * 2);
  bf16* wkb   = (bf16*)alloc((size_t)1024 * 1024 * 2);
  bf16* wvt   = (bf16*)alloc((size_t)8 * 128 * 4 * 1024 * 2);
  bf16* wot   = (bf16*)alloc((size_t)1024 * 4096 * 2);
  float* gate_v = (float*)alloc((size_t)8192 * 32 * 4);
  float* gate_o = (float*)alloc((size_t)8192 * 32 * 4);
  bf16* qsb   = (bf16*)alloc((size_t)8192 * 1024 * 2);   // bf16 copies of srcs
  bf16* ksb   = (bf16*)alloc((size_t)8192 * 1024 * 2);
  bf16* vsb   = (bf16*)alloc((size_t)8192 * 1024 * 2);
  bf16* qb    = (bf16*)alloc((size_t)8192 * 1024 * 2);   // [b,h,s,dh]
  bf16* kb    = (bf16*)alloc((size_t)8192 * 1024 * 2);   // [b,h,s,dh]
  bf16* vbT   = (bf16*)alloc((size_t)8192 * 1024 * 2);   // [b,h,dh,s]
  bf16* outb  = (bf16*)alloc((size_t)8192 * 1024 * 2);   // [b,s,h,dh]

  f32_to_bf16<<<4096, 256, 0, stream>>>(wq, wqb, 1024 * 1024);
  f32_to_bf16<<<4096, 256, 0, stream>>>(wk, wkb, 1024 * 1024);
  f32_to_bf16<<<32768, 256, 0, stream>>>(q_src, qsb, 8388608);
  f32_to_bf16<<<32768, 256, 0, stream>>>(k_src, ksb, 8388608);
  f32_to_bf16<<<32768, 256, 0, stream>>>(v_src, vsb, 8388608);
  make_wvt<<<16384, 256, 0, stream>>>(v_w, wvt);
  make_wot<<<16384, 256, 0, stream>>>(o_w, wot);
  gating<<<dim3(8192, 2), 256, 0, stream>>>(q_src, k_src, sel_v_w, sel_o_w,
                                            bias_v, bias_o, gate_v, gate_o, out);

  const float ssq = 0.29730177875068026f;            // 128^-0.25 (applied to both q and k)
  const float log2e = 1.4426950408889634f;
  gemm_moe<0><<<dim3(8, 64), 256, 0, stream>>>(qsb, wqb, nullptr, qb, nullptr, ssq * log2e);
  gemm_moe<0><<<dim3(8, 64), 256, 0, stream>>>(ksb, wkb, nullptr, kb, nullptr, ssq);
  gemm_moe<1><<<dim3(1, 64, 8), 256, 0, stream>>>(vsb, wvt, gate_v, vbT, nullptr, 1.0f);
  attn_kernel<<<dim3(32, 32), 256, 0, stream>>>(qb, kb, vbT, outb);
  gemm_moe<2><<<dim3(8, 64), 256, 0, stream>>>(outb, wot, gate_o, nullptr, out, 1.0f);
}

// Round 5
// 821.611 us; speedup vs baseline: 1.2253x; 1.2211x over previous
//
#include <hip/hip_runtime.h>
#include <cstdint>
#include <cstddef>

typedef __bf16 bf16;
typedef __bf16 bf16x4 __attribute__((ext_vector_type(4)));
typedef __bf16 bf16x8 __attribute__((ext_vector_type(8)));
typedef float  fx4    __attribute__((ext_vector_type(4)));

// Problem dims (fixed): B=4, S=2048, D=1024, H=8, E=4, DH=128, K_route=2

__global__ __launch_bounds__(256) void f32_to_bf16(const float* __restrict__ src,
                                                   bf16* __restrict__ dst, int n) {
  int i = blockIdx.x * 256 + threadIdx.x;
  if (i < n) dst[i] = (bf16)src[i];
}

// wvt layout [h][dh][e][k]  <- v_w[h][e][k][dh]   (per-head B^T: N=dh=128, K'=e*1024+k)
__global__ __launch_bounds__(256) void make_wvt(const float* __restrict__ v_w,
                                                bf16* __restrict__ wvt) {
  int i = blockIdx.x * 256 + threadIdx.x;           // 4194304
  int k = i & 1023, e = (i >> 10) & 3, dh = (i >> 12) & 127, h = i >> 19;
  wvt[i] = (bf16)v_w[(((size_t)(h * 4 + e) * 1024) + k) * 128 + dh];
}

// wot layout [d][h][e][dh]  <- o_w[h][e][dh][d]   (B^T: N=d=1024, K'=(h*4+e)*128+dh)
__global__ __launch_bounds__(256) void make_wot(const float* __restrict__ o_w,
                                                bf16* __restrict__ wot) {
  int i = blockIdx.x * 256 + threadIdx.x;           // 4194304
  int dh = i & 127, e = (i >> 7) & 3, h = (i >> 9) & 7, d = i >> 12;
  wot[i] = (bf16)o_w[(((size_t)(h * 4 + e) * 128) + dh) * 1024 + d];
}

// ---------------- gating: sigmoid + top-2 of 4 per (token, head), f64 for exact ranking --------
__global__ __launch_bounds__(256) void gating(const float* __restrict__ q_src,
                                              const float* __restrict__ k_src,
                                              const float* __restrict__ sel_v_w,
                                              const float* __restrict__ sel_o_w,
                                              const float* __restrict__ bias_v,
                                              const float* __restrict__ bias_o,
                                              float* __restrict__ gate_v,
                                              float* __restrict__ gate_o,
                                              float* __restrict__ d_out) {
  int m = blockIdx.x, g = blockIdx.y;
  const float* x = g ? q_src : k_src;
  const float* w = g ? sel_o_w : sel_v_w;
  const float* bias = g ? bias_o : bias_v;
  float* gate = g ? gate_o : gate_v;
  float* idxo = d_out + 8388608 + g * 131072;       // v_idx then o_idx, as float values

  __shared__ float xs[1024];
  __shared__ double part_s[32][8];
  __shared__ double sel_s[32];
  int t = threadIdx.x;
  #pragma unroll
  for (int p = 0; p < 4; p++) xs[t + p * 256] = x[(size_t)m * 1024 + t + p * 256];
  __syncthreads();
  int he = t >> 3, pp = t & 7;
  const float* wrow = w + he * 1024;
  double acc = 0.0;
  for (int j = 0; j < 128; j++) { int k = pp + j * 8; acc += (double)xs[k] * (double)wrow[k]; }
  part_s[he][pp] = acc;
  __syncthreads();
  if (t < 32) {
    double tot = 0.0;
    #pragma unroll
    for (int j = 0; j < 8; j++) tot += part_s[t][j];
    sel_s[t] = 1.0 / (1.0 + exp(-tot));
  }
  __syncthreads();
  if (t < 8) {
    double v[4], vbv[4];
    #pragma unroll
    for (int e = 0; e < 4; e++) { v[e] = sel_s[t * 4 + e]; vbv[e] = v[e] + (double)bias[e]; }
    int i0 = 0;
    for (int e = 1; e < 4; e++) if (vbv[e] > vbv[i0]) i0 = e;
    int i1 = -1; double best = -1e300;
    for (int e = 0; e < 4; e++) { if (e == i0) continue; if (vbv[e] > best) { best = vbv[e]; i1 = e; } }
    float* gp = gate + ((size_t)m * 8 + t) * 4;
    #pragma unroll
    for (int e = 0; e < 4; e++) {
      float gv = 0.f;
      if (e == i0) gv = (float)v[i0];
      else if (e == i1) gv = (float)v[i1];
      gp[e] = gv;
    }
    idxo[m * 16 + t * 2 + 0] = (float)i0;
    idxo[m * 16 + t * 2 + 1] = (float)i1;
  }
}

// ---------------- GEMM: C[M x N] = A' @ BT^T, bf16 MFMA 16x16x32, tile 128x128x64 ----------------
// MODE 0: A=bf16 src, BT=wq/wk (1024x1024); epilogue *scale -> bf16 [b,h,s,dh]
// MODE 1: per-head h=blockIdx.z: A'[m,e*1024+k]=vsb[m,k]*gate_v[m,h,e]; BT_h (128x4096);
//         epilogue (LDS transpose) -> vbT bf16 [b,h,dh,s]
// MODE 2: A'[m,(h*4+e)*128+dh]=outb[m,h,dh]*gate_o[m,h,e]; BT (1024x4096); epilogue f32 -> d_out
// NOTE: no waves-per-EU hint — measured: adding one cost ~50us aggregate (rounds 3/4).
template <int MODE>
__global__ __launch_bounds__(256) void gemm_moe(const bf16* __restrict__ Abf,
                                                const bf16* __restrict__ BT,
                                                const float* __restrict__ gate,
                                                bf16* __restrict__ Cbf,
                                                float* __restrict__ Cf32,
                                                float scale) {
  constexpr int KDIM = (MODE == 0) ? 1024 : 4096;
  __shared__ __align__(16) bf16 smem[18432];     // As: [0,9216)  Bs: [9216,18432), stride 72
  bf16* Asp = smem;
  bf16* Bsp = smem + 9216;
  const int t = threadIdx.x;
  const int wave = t >> 6, lane = t & 63;
  const int wr = wave >> 1, wc = wave & 1;
  const int quad = lane >> 4, l16 = lane & 15;
  const int m0 = blockIdx.y * 128;
  const int n0 = blockIdx.x * 128;
  const int h = (MODE == 1) ? blockIdx.z : 0;
  const bf16* BTh = (MODE == 1) ? BT + (size_t)h * 128 * 4096 : BT;

  fx4 acc[4][4] = {};

  const int arow = t >> 3, acol = (t & 7) * 8;    // 32 rows x 64 cols/pass, 4 passes

  for (int k0 = 0; k0 < KDIM; k0 += 64) {
    #pragma unroll
    for (int p = 0; p < 4; p++) {
      int m = m0 + arow + p * 32;
      bf16x8 u;
      if (MODE == 0) {
        u = *(const bf16x8*)(Abf + (size_t)m * 1024 + k0 + acol);
      } else if (MODE == 1) {
        int e = k0 >> 10;
        float gv = gate[((size_t)m * 8 + h) * 4 + e];
        u = *(const bf16x8*)(Abf + (size_t)m * 1024 + (k0 & 1023) + acol);
        #pragma unroll
        for (int j = 0; j < 8; j++) u[j] = (bf16)((float)u[j] * gv);
      } else {
        int kk = k0 + acol;
        int hh = kk >> 9, e = (kk >> 7) & 3, dh = kk & 127;
        float gv = gate[((size_t)m * 8 + hh) * 4 + e];
        u = *(const bf16x8*)(Abf + ((size_t)m * 8 + hh) * 128 + dh);
        #pragma unroll
        for (int j = 0; j < 8; j++) u[j] = (bf16)((float)u[j] * gv);
      }
      *(bf16x8*)(Asp + (arow + p * 32) * 72 + acol) = u;
    }
    #pragma unroll
    for (int p = 0; p < 4; p++) {
      int n = n0 + arow + p * 32;
      *(float4*)(Bsp + (arow + p * 32) * 72 + acol) = *(const float4*)(BTh + (size_t)n * KDIM + k0 + acol);
    }
    __syncthreads();
    #pragma unroll
    for (int kk = 0; kk < 64; kk += 32) {
      bf16x8 af[4], bfr[4];
      #pragma unroll
      for (int i = 0; i < 4; i++) af[i]  = *(const bf16x8*)(Asp + (wr * 64 + i * 16 + l16) * 72 + kk + quad * 8);
      #pragma unroll
      for (int i = 0; i < 4; i++) bfr[i] = *(const bf16x8*)(Bsp + (wc * 64 + i * 16 + l16) * 72 + kk + quad * 8);
      #pragma unroll
      for (int mi = 0; mi < 4; mi++)
        #pragma unroll
        for (int ni = 0; ni < 4; ni++)
          acc[mi][ni] = __builtin_amdgcn_mfma_f32_16x16x32_bf16(af[mi], bfr[ni], acc[mi][ni], 0, 0, 0);
    }
    __syncthreads();
  }

  if (MODE == 1) {
    // transpose through LDS -> vbT[b,h,dh,s] with coalesced global writes
    #pragma unroll
    for (int mi = 0; mi < 4; mi++)
      #pragma unroll
      for (int ni = 0; ni < 4; ni++) {
        int nl = wc * 64 + ni * 16 + l16;
        int ml = wr * 64 + mi * 16 + quad * 4;
        bf16x4 pk;
        #pragma unroll
        for (int r = 0; r < 4; r++) pk[r] = (bf16)acc[mi][ni][r];
        *(bf16x4*)(smem + nl * 136 + ml) = pk;   // T[n][m], stride 136
      }
    __syncthreads();
    int b = m0 >> 11, s0 = m0 & 2047;
    const int row = t >> 1, base = (t & 1) * 64;
    bf16* dst = Cbf + (((size_t)(b * 8 + h) * 128) + row) * 2048 + s0 + base;
    #pragma unroll
    for (int j = 0; j < 8; j++)
      *(float4*)(dst + j * 8) = *(float4*)(smem + row * 136 + base + j * 8);
    return;
  }

  // epilogue: C/D layout col=lane&15, row=quad*4+reg
  #pragma unroll
  for (int mi = 0; mi < 4; mi++)
    #pragma unroll
    for (int ni = 0; ni < 4; ni++)
      #pragma unroll
      for (int r = 0; r < 4; r++) {
        int m = m0 + wr * 64 + mi * 16 + quad * 4 + r;
        int n = n0 + wc * 64 + ni * 16 + l16;
        float v = acc[mi][ni][r] * scale;
        if (MODE == 0) {
          int b = m >> 11, s = m & 2047, hh = n >> 7, dh = n & 127;
          Cbf[(((size_t)(b * 8 + hh) * 2048 + s) << 7) + dh] = (bf16)v;
        } else {
          Cf32[(size_t)m * 1024 + n] = v;
        }
      }
}

// ---------------- flash attention (causal), per (b,h) x 64-row q-tile ----------------
// Direct global->LDS staging (NO register prefetch: rounds 2-4 proved the compiler spills
// float4 prefetch regs held across barriers -> 340 MB/call scratch traffic; round 1's
// direct staging had zero spill). Latency hiding via 3 blocks/CU occupancy instead.
__global__ __launch_bounds__(256) void attn_kernel(const bf16* __restrict__ qb,
                                                   const bf16* __restrict__ kb,
                                                   const bf16* __restrict__ vbT,
                                                   bf16* __restrict__ outb) {
  const int qt = 31 - blockIdx.x;   // heavy blocks dispatch first
  const int bh = blockIdx.y;
  const int b = bh >> 3, h = bh & 7;
  __shared__ __align__(16) bf16 Ks[64][136];
  __shared__ __align__(16) bf16 VTs[128][72];
  __shared__ __align__(16) bf16 Ps[4][16][72];
  const int t = threadIdx.x, wave = t >> 6, lane = t & 63;
  const int quad = lane >> 4, l16 = lane & 15;
  const bf16* qbase  = qb  + (size_t)bh * 2048 * 128;
  const bf16* kbase  = kb  + (size_t)bh * 2048 * 128;
  const bf16* vtbase = vbT + (size_t)bh * 128 * 2048;

  // stage Q through Ks (one-time), read q-fragments into registers
  #pragma unroll
  for (int p = 0; p < 4; p++) {
    int c = t + p * 256;
    *(float4*)&Ks[c >> 4][(c & 15) * 8] =
        *(const float4*)(qbase + (size_t)(qt * 64 + (c >> 4)) * 128 + (c & 15) * 8);
  }
  __syncthreads();
  bf16x8 qf[4];
  #pragma unroll
  for (int dk = 0; dk < 4; dk++) qf[dk] = *(const bf16x8*)&Ks[wave * 16 + l16][dk * 32 + quad * 8];

  float m_run[4], l_run[4];
  fx4 acc_o[8] = {};
  #pragma unroll
  for (int r = 0; r < 4; r++) { m_run[r] = -1e30f; l_run[r] = 0.f; }

  for (int kt = 0; kt <= qt; kt++) {
    __syncthreads();                 // all waves done reading Ks/VTs (or qf on iter 0)
    #pragma unroll
    for (int p = 0; p < 4; p++) {
      int c = t + p * 256;
      *(float4*)&Ks[c >> 4][(c & 15) * 8] =
          *(const float4*)(kbase + (size_t)(kt * 64 + (c >> 4)) * 128 + (c & 15) * 8);
      *(float4*)&VTs[c >> 3][(c & 7) * 8] =
          *(const float4*)(vtbase + (size_t)(c >> 3) * 2048 + kt * 64 + (c & 7) * 8);
    }
    __syncthreads();

    fx4 accs[4] = {};
    #pragma unroll
    for (int ni = 0; ni < 4; ni++)
      #pragma unroll
      for (int dk = 0; dk < 4; dk++) {
        bf16x8 kf = *(const bf16x8*)&Ks[ni * 16 + l16][dk * 32 + quad * 8];
        accs[ni] = __builtin_amdgcn_mfma_f32_16x16x32_bf16(qf[dk], kf, accs[ni], 0, 0, 0);
      }

    if (kt == qt) {   // causal mask on the diagonal tile
      #pragma unroll
      for (int ni = 0; ni < 4; ni++)
        #pragma unroll
        for (int r = 0; r < 4; r++) {
          int qr = wave * 16 + quad * 4 + r;
          int kc = ni * 16 + l16;
          if (kc > qr) accs[ni][r] = -1e30f;
        }
    }

    // softmax in exp2 domain (log2e folded into Q scale); exp results overwrite accs
    #pragma unroll
    for (int r = 0; r < 4; r++) {
      float mx = fmaxf(fmaxf(accs[0][r], accs[1][r]), fmaxf(accs[2][r], accs[3][r]));
      #pragma unroll
      for (int s = 1; s < 16; s <<= 1) mx = fmaxf(mx, __shfl_xor(mx, s, 64));
      float m_new = fmaxf(m_run[r], mx);
      float alpha = __builtin_amdgcn_exp2f(m_run[r] - m_new);
      float rs = 0.f;
      #pragma unroll
      for (int ni = 0; ni < 4; ni++) {
        float p = __builtin_amdgcn_exp2f(accs[ni][r] - m_new);
        accs[ni][r] = p; rs += p;
      }
      #pragma unroll
      for (int s = 1; s < 16; s <<= 1) rs += __shfl_xor(rs, s, 64);
      l_run[r] = l_run[r] * alpha + rs;
      m_run[r] = m_new;
      #pragma unroll
      for (int nj = 0; nj < 8; nj++) acc_o[nj][r] *= alpha;
    }

    // P: C-layout -> LDS -> A-layout (per-wave region; DS in-order within a wave)
    #pragma unroll
    for (int ni = 0; ni < 4; ni++)
      #pragma unroll
      for (int r = 0; r < 4; r++)
        Ps[wave][quad * 4 + r][ni * 16 + l16] = (bf16)accs[ni][r];

    #pragma unroll
    for (int step = 0; step < 2; step++) {
      bf16x8 pf = *(const bf16x8*)&Ps[wave][l16][step * 32 + quad * 8];
      #pragma unroll
      for (int nj = 0; nj < 8; nj++) {
        bf16x8 vf = *(const bf16x8*)&VTs[nj * 16 + l16][step * 32 + quad * 8];
        acc_o[nj] = __builtin_amdgcn_mfma_f32_16x16x32_bf16(pf, vf, acc_o[nj], 0, 0, 0);
      }
    }
  }

  #pragma unroll
  for (int nj = 0; nj < 8; nj++)
    #pragma unroll
    for (int r = 0; r < 4; r++) {
      int s = qt * 64 + wave * 16 + quad * 4 + r;
      int token = b * 2048 + s;
      float o = acc_o[nj][r] / l_run[r];
      outb[((size_t)token * 8 + h) * 128 + nj * 16 + l16] = (bf16)o;
    }
}

// ---------------- launch ----------------
extern "C" void kernel_launch(void* const* d_in, const int* in_sizes, int n_in,
                              void* d_out, int out_size, void* d_ws, size_t ws_size,
                              hipStream_t stream) {
  const float* q_src  = (const float*)d_in[0];
  const float* k_src  = (const float*)d_in[1];
  const float* v_src  = (const float*)d_in[2];
  const float* wq     = (const float*)d_in[3];
  const float* wk     = (const float*)d_in[4];
  const float* sel_v_w = (const float*)d_in[5];
  const float* sel_o_w = (const float*)d_in[6];
  const float* v_w    = (const float*)d_in[7];
  const float* o_w    = (const float*)d_in[8];
  const float* bias_v = (const float*)d_in[9];
  const float* bias_o = (const float*)d_in[10];
  float* out = (float*)d_out;

  char* ws = (char*)d_ws;
  size_t off = 0;
  auto alloc = [&](size_t bytes) { char* p = ws + off; off += (bytes + 255) & ~(size_t)255; return p; };
  bf16* wqb   = (bf16*)alloc((size_t)1024 * 1024 * 2);
  bf16* wkb   = (bf16*)alloc((size_t)1024 * 1024 * 2);
  bf16* wvt   = (bf16*)alloc((size_t)8 * 128 * 4 * 1024 * 2);
  bf16* wot   = (bf16*)alloc((size_t)1024 * 4096 * 2);
  float* gate_v = (float*)alloc((size_t)8192 * 32 * 4);
  float* gate_o = (float*)alloc((size_t)8192 * 32 * 4);
  bf16* qsb   = (bf16*)alloc((size_t)8192 * 1024 * 2);   // bf16 copies of srcs
  bf16* ksb   = (bf16*)alloc((size_t)8192 * 1024 * 2);
  bf16* vsb   = (bf16*)alloc((size_t)8192 * 1024 * 2);
  bf16* qb    = (bf16*)alloc((size_t)8192 * 1024 * 2);   // [b,h,s,dh]
  bf16* kb    = (bf16*)alloc((size_t)8192 * 1024 * 2);   // [b,h,s,dh]
  bf16* vbT   = (bf16*)alloc((size_t)8192 * 1024 * 2);   // [b,h,dh,s]
  bf16* outb  = (bf16*)alloc((size_t)8192 * 1024 * 2);   // [b,s,h,dh]

  f32_to_bf16<<<4096, 256, 0, stream>>>(wq, wqb, 1024 * 1024);
  f32_to_bf16<<<4096, 256, 0, stream>>>(wk, wkb, 1024 * 1024);
  f32_to_bf16<<<32768, 256, 0, stream>>>(q_src, qsb, 8388608);
  f32_to_bf16<<<32768, 256, 0, stream>>>(k_src, ksb, 8388608);
  f32_to_bf16<<<32768, 256, 0, stream>>>(v_src, vsb, 8388608);
  make_wvt<<<16384, 256, 0, stream>>>(v_w, wvt);
  make_wot<<<16384, 256, 0, stream>>>(o_w, wot);
  gating<<<dim3(8192, 2), 256, 0, stream>>>(q_src, k_src, sel_v_w, sel_o_w,
                                            bias_v, bias_o, gate_v, gate_o, out);

  const float ssq = 0.29730177875068026f;            // 128^-0.25 (applied to both q and k)
  const float log2e = 1.4426950408889634f;
  gemm_moe<0><<<dim3(8, 64), 256, 0, stream>>>(qsb, wqb, nullptr, qb, nullptr, ssq * log2e);
  gemm_moe<0><<<dim3(8, 64), 256, 0, stream>>>(ksb, wkb, nullptr, kb, nullptr, ssq);
  gemm_moe<1><<<dim3(1, 64, 8), 256, 0, stream>>>(vsb, wvt, gate_v, vbT, nullptr, 1.0f);
  attn_kernel<<<dim3(32, 32), 256, 0, stream>>>(qb, kb, vbT, outb);
  gemm_moe<2><<<dim3(8, 64), 256, 0, stream>>>(outb, wot, gate_o, nullptr, out, 1.0f);
}

// Round 6
// 798.279 us; speedup vs baseline: 1.2612x; 1.0292x over previous
//
#include <hip/hip_runtime.h>
#include <cstdint>
#include <cstddef>

typedef __bf16 bf16;
typedef __bf16 bf16x4 __attribute__((ext_vector_type(4)));
typedef __bf16 bf16x8 __attribute__((ext_vector_type(8)));
typedef float  fx4    __attribute__((ext_vector_type(4)));

// Problem dims (fixed): B=4, S=2048, D=1024, H=8, E=4, DH=128, K_route=2

// async global->LDS DMA, 16 B per lane; dest = wave-uniform base + lane*16 (m97/m104)
__device__ __forceinline__ void async16(const bf16* g, bf16* l) {
  __builtin_amdgcn_global_load_lds((const __attribute__((address_space(1))) void*)g,
                                   (__attribute__((address_space(3))) void*)l, 16, 0, 0);
}

__global__ __launch_bounds__(256) void f32_to_bf16(const float* __restrict__ src,
                                                   bf16* __restrict__ dst, int n) {
  int i = blockIdx.x * 256 + threadIdx.x;
  if (i < n) dst[i] = (bf16)src[i];
}

// wvt[h][dh][e][k] <- v_w[h][e][k][dh]; LDS-tiled 64x64 transpose, coalesced both sides.
// grid (16 ktiles, 2 dhtiles, 32 he)
__global__ __launch_bounds__(256) void make_wvt(const float* __restrict__ v_w,
                                                bf16* __restrict__ wvt) {
  __shared__ float tile[64][65];
  const int he = blockIdx.z, k0 = blockIdx.x * 64, dh0 = blockIdx.y * 64;
  const float* in = v_w + (size_t)he * 1024 * 128;
  #pragma unroll
  for (int j = 0; j < 16; j++) {
    int idx = threadIdx.x + j * 256;
    int r = idx >> 6, c = idx & 63;                 // r=k, c=dh
    tile[r][c] = in[(size_t)(k0 + r) * 128 + dh0 + c];
  }
  __syncthreads();
  const int h = he >> 2, e = he & 3;
  bf16* outp = wvt + ((size_t)(h * 128 + dh0) * 4 + e) * 1024 + k0;
  #pragma unroll
  for (int j = 0; j < 16; j++) {
    int idx = threadIdx.x + j * 256;
    int r = idx >> 6, c = idx & 63;                 // r=dh, c=k
    outp[(size_t)r * 4096 + c] = (bf16)tile[c][r];
  }
}

// wot[d][h][e][dh] <- o_w[h][e][dh][d]; grid (16 dtiles, 2 dhtiles, 32 he)
__global__ __launch_bounds__(256) void make_wot(const float* __restrict__ o_w,
                                                bf16* __restrict__ wot) {
  __shared__ float tile[64][65];
  const int he = blockIdx.z, d0 = blockIdx.x * 64, dh0 = blockIdx.y * 64;
  const float* in = o_w + (size_t)he * 128 * 1024;
  #pragma unroll
  for (int j = 0; j < 16; j++) {
    int idx = threadIdx.x + j * 256;
    int r = idx >> 6, c = idx & 63;                 // r=dh, c=d
    tile[r][c] = in[(size_t)(dh0 + r) * 1024 + d0 + c];
  }
  __syncthreads();
  bf16* outp = wot + (size_t)d0 * 4096 + he * 128 + dh0;
  #pragma unroll
  for (int j = 0; j < 16; j++) {
    int idx = threadIdx.x + j * 256;
    int r = idx >> 6, c = idx & 63;                 // r=d, c=dh
    outp[(size_t)r * 4096 + c] = (bf16)tile[c][r];
  }
}

// ---------------- gating: sigmoid + top-2 of 4 per (token, head), f64 for exact ranking --------
__global__ __launch_bounds__(256) void gating(const float* __restrict__ q_src,
                                              const float* __restrict__ k_src,
                                              const float* __restrict__ sel_v_w,
                                              const float* __restrict__ sel_o_w,
                                              const float* __restrict__ bias_v,
                                              const float* __restrict__ bias_o,
                                              float* __restrict__ gate_v,
                                              float* __restrict__ gate_o,
                                              float* __restrict__ d_out) {
  int m = blockIdx.x, g = blockIdx.y;
  const float* x = g ? q_src : k_src;
  const float* w = g ? sel_o_w : sel_v_w;
  const float* bias = g ? bias_o : bias_v;
  float* gate = g ? gate_o : gate_v;
  float* idxo = d_out + 8388608 + g * 131072;       // v_idx then o_idx, as float values

  __shared__ float xs[1024];
  __shared__ double part_s[32][8];
  __shared__ double sel_s[32];
  int t = threadIdx.x;
  #pragma unroll
  for (int p = 0; p < 4; p++) xs[t + p * 256] = x[(size_t)m * 1024 + t + p * 256];
  __syncthreads();
  int he = t >> 3, pp = t & 7;
  const float* wrow = w + he * 1024;
  double acc = 0.0;
  for (int j = 0; j < 128; j++) { int k = pp + j * 8; acc += (double)xs[k] * (double)wrow[k]; }
  part_s[he][pp] = acc;
  __syncthreads();
  if (t < 32) {
    double tot = 0.0;
    #pragma unroll
    for (int j = 0; j < 8; j++) tot += part_s[t][j];
    sel_s[t] = 1.0 / (1.0 + exp(-tot));
  }
  __syncthreads();
  if (t < 8) {
    double v[4], vbv[4];
    #pragma unroll
    for (int e = 0; e < 4; e++) { v[e] = sel_s[t * 4 + e]; vbv[e] = v[e] + (double)bias[e]; }
    int i0 = 0;
    for (int e = 1; e < 4; e++) if (vbv[e] > vbv[i0]) i0 = e;
    int i1 = -1; double best = -1e300;
    for (int e = 0; e < 4; e++) { if (e == i0) continue; if (vbv[e] > best) { best = vbv[e]; i1 = e; } }
    float* gp = gate + ((size_t)m * 8 + t) * 4;
    #pragma unroll
    for (int e = 0; e < 4; e++) {
      float gv = 0.f;
      if (e == i0) gv = (float)v[i0];
      else if (e == i1) gv = (float)v[i1];
      gp[e] = gv;
    }
    idxo[m * 16 + t * 2 + 0] = (float)i0;
    idxo[m * 16 + t * 2 + 1] = (float)i1;
  }
}

// ---------------- GEMM: C[M x N] = A' @ BT^T, bf16 MFMA 16x16x32, tile 128x128x64 ----------------
// m97-style staging: B (all modes) + A (MODE 0) via global_load_lds dwordx4 into UNPADDED
// stride-64 tiles (the 874 TF recipe). A for modes 1/2 is VALU-staged (gate multiply) padded.
// MODE 0: A=bf16 src, BT=wq/wk (1024x1024); epilogue *scale -> bf16 [b,h,s,dh]
// MODE 1: per-head h=blockIdx.z: A'[m,e*1024+k]=vsb[m,k]*gate_v[m,h,e]; BT_h (128x4096);
//         epilogue (LDS transpose) -> vbT bf16 [b,h,dh,s]
// MODE 2: A'[m,(h*4+e)*128+dh]=outb[m,h,dh]*gate_o[m,h,e]; BT (1024x4096); epilogue f32 -> d_out
template <int MODE>
__global__ __launch_bounds__(256) void gemm_moe(const bf16* __restrict__ Abf,
                                                const bf16* __restrict__ BT,
                                                const float* __restrict__ gate,
                                                bf16* __restrict__ Cbf,
                                                float* __restrict__ Cf32,
                                                float scale) {
  constexpr int KDIM = (MODE == 0) ? 1024 : 4096;
  constexpr int ASTR = (MODE == 0) ? 64 : 72;
  constexpr int ASZ = 128 * ASTR;
  __shared__ __align__(16) bf16 smem[ASZ + 128 * 64];   // As then Bs
  bf16* Asp = smem;
  bf16* Bsp = smem + ASZ;
  const int t = threadIdx.x;
  const int wave = t >> 6, lane = t & 63;
  const int wr = wave >> 1, wc = wave & 1;
  const int quad = lane >> 4, l16 = lane & 15;
  const int m0 = blockIdx.y * 128;
  const int n0 = blockIdx.x * 128;
  const int h = (MODE == 1) ? blockIdx.z : 0;
  const bf16* BTh = (MODE == 1) ? BT + (size_t)h * 128 * 4096 : BT;

  fx4 acc[4][4] = {};

  const int drow = lane >> 3, dcol = (lane & 7) * 8;   // DMA: 8 rows x 64 cols per wave-pass
  const int arow = t >> 3, acol = (t & 7) * 8;         // VALU staging mapping

  for (int k0 = 0; k0 < KDIM; k0 += 64) {
    // ---- B staging: DMA, 4 passes x (8 rows/wave) ----
    #pragma unroll
    for (int p = 0; p < 4; p++) {
      int rbase = p * 32 + wave * 8;
      async16(BTh + (size_t)(n0 + rbase + drow) * KDIM + k0 + dcol,
              Bsp + rbase * 64 + lane * 8);
    }
    // ---- A staging ----
    if (MODE == 0) {
      #pragma unroll
      for (int p = 0; p < 4; p++) {
        int rbase = p * 32 + wave * 8;
        async16(Abf + (size_t)(m0 + rbase + drow) * 1024 + k0 + dcol,
                Asp + rbase * 64 + lane * 8);
      }
    } else if (MODE == 1) {
      int e = k0 >> 10;
      #pragma unroll
      for (int p = 0; p < 4; p++) {
        int m = m0 + arow + p * 32;
        float gv = gate[((size_t)m * 8 + h) * 4 + e];
        bf16x8 u = *(const bf16x8*)(Abf + (size_t)m * 1024 + (k0 & 1023) + acol);
        #pragma unroll
        for (int j = 0; j < 8; j++) u[j] = (bf16)((float)u[j] * gv);
        *(bf16x8*)(Asp + (arow + p * 32) * 72 + acol) = u;
      }
    } else {
      int kk = k0 + acol;
      int hh = kk >> 9, e = (kk >> 7) & 3, dh = kk & 127;
      #pragma unroll
      for (int p = 0; p < 4; p++) {
        int m = m0 + arow + p * 32;
        float gv = gate[((size_t)m * 8 + hh) * 4 + e];
        bf16x8 u = *(const bf16x8*)(Abf + ((size_t)m * 8 + hh) * 128 + dh);
        #pragma unroll
        for (int j = 0; j < 8; j++) u[j] = (bf16)((float)u[j] * gv);
        *(bf16x8*)(Asp + (arow + p * 32) * 72 + acol) = u;
      }
    }
    __syncthreads();   // drains vmcnt (DMA) + lgkmcnt before fragment reads
    #pragma unroll
    for (int kk = 0; kk < 64; kk += 32) {
      bf16x8 af[4], bfr[4];
      #pragma unroll
      for (int i = 0; i < 4; i++) af[i]  = *(const bf16x8*)(Asp + (wr * 64 + i * 16 + l16) * ASTR + kk + quad * 8);
      #pragma unroll
      for (int i = 0; i < 4; i++) bfr[i] = *(const bf16x8*)(Bsp + (wc * 64 + i * 16 + l16) * 64 + kk + quad * 8);
      #pragma unroll
      for (int mi = 0; mi < 4; mi++)
        #pragma unroll
        for (int ni = 0; ni < 4; ni++)
          acc[mi][ni] = __builtin_amdgcn_mfma_f32_16x16x32_bf16(af[mi], bfr[ni], acc[mi][ni], 0, 0, 0);
    }
    __syncthreads();
  }

  if (MODE == 1) {
    // transpose through LDS -> vbT[b,h,dh,s] with coalesced global writes
    #pragma unroll
    for (int mi = 0; mi < 4; mi++)
      #pragma unroll
      for (int ni = 0; ni < 4; ni++) {
        int nl = wc * 64 + ni * 16 + l16;
        int ml = wr * 64 + mi * 16 + quad * 4;
        bf16x4 pk;
        #pragma unroll
        for (int r = 0; r < 4; r++) pk[r] = (bf16)acc[mi][ni][r];
        *(bf16x4*)(smem + nl * 136 + ml) = pk;   // T[n][m], stride 136 (17408 = ASZ+8192)
      }
    __syncthreads();
    int b = m0 >> 11, s0 = m0 & 2047;
    const int row = t >> 1, base = (t & 1) * 64;
    bf16* dst = Cbf + (((size_t)(b * 8 + h) * 128) + row) * 2048 + s0 + base;
    #pragma unroll
    for (int j = 0; j < 8; j++)
      *(float4*)(dst + j * 8) = *(float4*)(smem + row * 136 + base + j * 8);
    return;
  }

  // epilogue: C/D layout col=lane&15, row=quad*4+reg
  #pragma unroll
  for (int mi = 0; mi < 4; mi++)
    #pragma unroll
    for (int ni = 0; ni < 4; ni++)
      #pragma unroll
      for (int r = 0; r < 4; r++) {
        int m = m0 + wr * 64 + mi * 16 + quad * 4 + r;
        int n = n0 + wc * 64 + ni * 16 + l16;
        float v = acc[mi][ni][r] * scale;
        if (MODE == 0) {
          int b = m >> 11, s = m & 2047, hh = n >> 7, dh = n & 127;
          Cbf[(((size_t)(b * 8 + hh) * 2048 + s) << 7) + dh] = (bf16)v;
        } else {
          Cf32[(size_t)m * 1024 + n] = v;
        }
      }
}

// ---------------- flash attention (causal), per (b,h) x 64-row q-tile ----------------
// Direct global->LDS staging (NO register prefetch: rounds 2-4 proved the compiler spills
// float4 prefetch regs held across barriers -> 340 MB/call scratch traffic).
__global__ __launch_bounds__(256) void attn_kernel(const bf16* __restrict__ qb,
                                                   const bf16* __restrict__ kb,
                                                   const bf16* __restrict__ vbT,
                                                   bf16* __restrict__ outb) {
  const int qt = 31 - blockIdx.x;   // heavy blocks dispatch first
  const int bh = blockIdx.y;
  const int b = bh >> 3, h = bh & 7;
  __shared__ __align__(16) bf16 Ks[64][136];
  __shared__ __align__(16) bf16 VTs[128][72];
  __shared__ __align__(16) bf16 Ps[4][16][72];
  const int t = threadIdx.x, wave = t >> 6, lane = t & 63;
  const int quad = lane >> 4, l16 = lane & 15;
  const bf16* qbase  = qb  + (size_t)bh * 2048 * 128;
  const bf16* kbase  = kb  + (size_t)bh * 2048 * 128;
  const bf16* vtbase = vbT + (size_t)bh * 128 * 2048;

  // stage Q through Ks (one-time), read q-fragments into registers
  #pragma unroll
  for (int p = 0; p < 4; p++) {
    int c = t + p * 256;
    *(float4*)&Ks[c >> 4][(c & 15) * 8] =
        *(const float4*)(qbase + (size_t)(qt * 64 + (c >> 4)) * 128 + (c & 15) * 8);
  }
  __syncthreads();
  bf16x8 qf[4];
  #pragma unroll
  for (int dk = 0; dk < 4; dk++) qf[dk] = *(const bf16x8*)&Ks[wave * 16 + l16][dk * 32 + quad * 8];

  float m_run[4], l_run[4];
  fx4 acc_o[8] = {};
  #pragma unroll
  for (int r = 0; r < 4; r++) { m_run[r] = -1e30f; l_run[r] = 0.f; }

  for (int kt = 0; kt <= qt; kt++) {
    __syncthreads();                 // all waves done reading Ks/VTs (or qf on iter 0)
    #pragma unroll
    for (int p = 0; p < 4; p++) {
      int c = t + p * 256;
      *(float4*)&Ks[c >> 4][(c & 15) * 8] =
          *(const float4*)(kbase + (size_t)(kt * 64 + (c >> 4)) * 128 + (c & 15) * 8);
      *(float4*)&VTs[c >> 3][(c & 7) * 8] =
          *(const float4*)(vtbase + (size_t)(c >> 3) * 2048 + kt * 64 + (c & 7) * 8);
    }
    __syncthreads();

    fx4 accs[4] = {};
    #pragma unroll
    for (int ni = 0; ni < 4; ni++)
      #pragma unroll
      for (int dk = 0; dk < 4; dk++) {
        bf16x8 kf = *(const bf16x8*)&Ks[ni * 16 + l16][dk * 32 + quad * 8];
        accs[ni] = __builtin_amdgcn_mfma_f32_16x16x32_bf16(qf[dk], kf, accs[ni], 0, 0, 0);
      }

    if (kt == qt) {   // causal mask on the diagonal tile
      #pragma unroll
      for (int ni = 0; ni < 4; ni++)
        #pragma unroll
        for (int r = 0; r < 4; r++) {
          int qr = wave * 16 + quad * 4 + r;
          int kc = ni * 16 + l16;
          if (kc > qr) accs[ni][r] = -1e30f;
        }
    }

    // softmax in exp2 domain (log2e folded into Q scale); exp results overwrite accs
    #pragma unroll
    for (int r = 0; r < 4; r++) {
      float mx = fmaxf(fmaxf(accs[0][r], accs[1][r]), fmaxf(accs[2][r], accs[3][r]));
      #pragma unroll
      for (int s = 1; s < 16; s <<= 1) mx = fmaxf(mx, __shfl_xor(mx, s, 64));
      float m_new = fmaxf(m_run[r], mx);
      float alpha = __builtin_amdgcn_exp2f(m_run[r] - m_new);
      float rs = 0.f;
      #pragma unroll
      for (int ni = 0; ni < 4; ni++) {
        float p = __builtin_amdgcn_exp2f(accs[ni][r] - m_new);
        accs[ni][r] = p; rs += p;
      }
      #pragma unroll
      for (int s = 1; s < 16; s <<= 1) rs += __shfl_xor(rs, s, 64);
      l_run[r] = l_run[r] * alpha + rs;
      m_run[r] = m_new;
      #pragma unroll
      for (int nj = 0; nj < 8; nj++) acc_o[nj][r] *= alpha;
    }

    // P: C-layout -> LDS -> A-layout (per-wave region; DS in-order within a wave)
    #pragma unroll
    for (int ni = 0; ni < 4; ni++)
      #pragma unroll
      for (int r = 0; r < 4; r++)
        Ps[wave][quad * 4 + r][ni * 16 + l16] = (bf16)accs[ni][r];

    #pragma unroll
    for (int step = 0; step < 2; step++) {
      bf16x8 pf = *(const bf16x8*)&Ps[wave][l16][step * 32 + quad * 8];
      #pragma unroll
      for (int nj = 0; nj < 8; nj++) {
        bf16x8 vf = *(const bf16x8*)&VTs[nj * 16 + l16][step * 32 + quad * 8];
        acc_o[nj] = __builtin_amdgcn_mfma_f32_16x16x32_bf16(pf, vf, acc_o[nj], 0, 0, 0);
      }
    }
  }

  #pragma unroll
  for (int nj = 0; nj < 8; nj++)
    #pragma unroll
    for (int r = 0; r < 4; r++) {
      int s = qt * 64 + wave * 16 + quad * 4 + r;
      int token = b * 2048 + s;
      float o = acc_o[nj][r] / l_run[r];
      outb[((size_t)token * 8 + h) * 128 + nj * 16 + l16] = (bf16)o;
    }
}

// ---------------- launch ----------------
extern "C" void kernel_launch(void* const* d_in, const int* in_sizes, int n_in,
                              void* d_out, int out_size, void* d_ws, size_t ws_size,
                              hipStream_t stream) {
  const float* q_src  = (const float*)d_in[0];
  const float* k_src  = (const float*)d_in[1];
  const float* v_src  = (const float*)d_in[2];
  const float* wq     = (const float*)d_in[3];
  const float* wk     = (const float*)d_in[4];
  const float* sel_v_w = (const float*)d_in[5];
  const float* sel_o_w = (const float*)d_in[6];
  const float* v_w    = (const float*)d_in[7];
  const float* o_w    = (const float*)d_in[8];
  const float* bias_v = (const float*)d_in[9];
  const float* bias_o = (const float*)d_in[10];
  float* out = (float*)d_out;

  char* ws = (char*)d_ws;
  size_t off = 0;
  auto alloc = [&](size_t bytes) { char* p = ws + off; off += (bytes + 255) & ~(size_t)255; return p; };
  bf16* wqb   = (bf16*)alloc((size_t)1024 * 1024 * 2);
  bf16* wkb   = (bf16*)alloc((size_t)1024 * 1024 * 2);
  bf16* wvt   = (bf16*)alloc((size_t)8 * 128 * 4 * 1024 * 2);
  bf16* wot   = (bf16*)alloc((size_t)1024 * 4096 * 2);
  float* gate_v = (float*)alloc((size_t)8192 * 32 * 4);
  float* gate_o = (float*)alloc((size_t)8192 * 32 * 4);
  bf16* qsb   = (bf16*)alloc((size_t)8192 * 1024 * 2);   // bf16 copies of srcs
  bf16* ksb   = (bf16*)alloc((size_t)8192 * 1024 * 2);
  bf16* vsb   = (bf16*)alloc((size_t)8192 * 1024 * 2);
  bf16* qb    = (bf16*)alloc((size_t)8192 * 1024 * 2);   // [b,h,s,dh]
  bf16* kb    = (bf16*)alloc((size_t)8192 * 1024 * 2);   // [b,h,s,dh]
  bf16* vbT   = (bf16*)alloc((size_t)8192 * 1024 * 2);   // [b,h,dh,s]
  bf16* outb  = (bf16*)alloc((size_t)8192 * 1024 * 2);   // [b,s,h,dh]

  f32_to_bf16<<<4096, 256, 0, stream>>>(wq, wqb, 1024 * 1024);
  f32_to_bf16<<<4096, 256, 0, stream>>>(wk, wkb, 1024 * 1024);
  f32_to_bf16<<<32768, 256, 0, stream>>>(q_src, qsb, 8388608);
  f32_to_bf16<<<32768, 256, 0, stream>>>(k_src, ksb, 8388608);
  f32_to_bf16<<<32768, 256, 0, stream>>>(v_src, vsb, 8388608);
  make_wvt<<<dim3(16, 2, 32), 256, 0, stream>>>(v_w, wvt);
  make_wot<<<dim3(16, 2, 32), 256, 0, stream>>>(o_w, wot);
  gating<<<dim3(8192, 2), 256, 0, stream>>>(q_src, k_src, sel_v_w, sel_o_w,
                                            bias_v, bias_o, gate_v, gate_o, out);

  const float ssq = 0.29730177875068026f;            // 128^-0.25 (applied to both q and k)
  const float log2e = 1.4426950408889634f;
  gemm_moe<0><<<dim3(8, 64), 256, 0, stream>>>(qsb, wqb, nullptr, qb, nullptr, ssq * log2e);
  gemm_moe<0><<<dim3(8, 64), 256, 0, stream>>>(ksb, wkb, nullptr, kb, nullptr, ssq);
  gemm_moe<1><<<dim3(1, 64, 8), 256, 0, stream>>>(vsb, wvt, gate_v, vbT, nullptr, 1.0f);
  attn_kernel<<<dim3(32, 32), 256, 0, stream>>>(qb, kb, vbT, outb);
  gemm_moe<2><<<dim3(8, 64), 256, 0, stream>>>(outb, wot, gate_o, nullptr, out, 1.0f);
}